// Round 4
// baseline (2436.874 us; speedup 1.0000x reference)
//
#include <hip/hip_runtime.h>

#define N_NODES 100000
#define E_EDGES 3200000
#define IN_F 512
#define H_F 32
#define OUT_F 64
#define BN_EPS 1e-5f
#define NBINS 1563              // ceil(100000 / 64), 64 nodes per bin

// ---------------- BN fold ----------------
__global__ void k_scales(const float* __restrict__ gamma, const float* __restrict__ beta,
                         const float* __restrict__ rm, const float* __restrict__ rv,
                         const float* __restrict__ b1,
                         float* __restrict__ scale, float* __restrict__ shift) {
    int k = threadIdx.x;
    if (k < H_F) {
        float s = gamma[k] * rsqrtf(rv[k] + BN_EPS);
        scale[k] = s;
        shift[k] = (b1[k] - rm[k]) * s + beta[k];
    }
}

// ---------------- bin histogram (LDS-privatized) ----------------
__global__ __launch_bounds__(256) void k_hist(const int* __restrict__ dst,
                                              unsigned* __restrict__ binCnt) {
    __shared__ unsigned h[NBINS];
    for (int i = threadIdx.x; i < NBINS; i += 256) h[i] = 0;
    __syncthreads();
    for (int e = blockIdx.x * 256 + threadIdx.x; e < E_EDGES; e += 256 * 512)
        atomicAdd(&h[((unsigned)dst[e]) >> 6], 1u);
    __syncthreads();
    for (int i = threadIdx.x; i < NBINS; i += 256) {
        unsigned v = h[i];
        if (v) atomicAdd(&binCnt[i], v);
    }
}

// ---------------- exclusive scan over 1563 bins (1 block) ----------------
__global__ __launch_bounds__(256) void k_scanbins(const unsigned* __restrict__ binCnt,
                                                  unsigned* __restrict__ binOff) {
    __shared__ unsigned carry;
    __shared__ unsigned wtot[4];
    if (threadIdx.x == 0) carry = 0;
    __syncthreads();
    int lane = threadIdx.x & 63, wid = threadIdx.x >> 6;
    for (int base = 0; base < NBINS; base += 256) {
        int i = base + (int)threadIdx.x;
        unsigned v = (i < NBINS) ? binCnt[i] : 0u;
        unsigned xs = v;
#pragma unroll
        for (int s = 1; s < 64; s <<= 1) {
            unsigned t = __shfl_up(xs, s, 64);
            if (lane >= s) xs += t;
        }
        if (lane == 63) wtot[wid] = xs;
        __syncthreads();
        unsigned wbase = 0, tot = 0;
#pragma unroll
        for (int w = 0; w < 4; ++w) { if (w < wid) wbase += wtot[w]; tot += wtot[w]; }
        if (i < NBINS) binOff[i] = carry + wbase + xs - v;
        __syncthreads();
        if (threadIdx.x == 0) carry += tot;
        __syncthreads();
    }
}

// ---------------- bin fill: packed = (d_local<<17) | src ----------------
__global__ __launch_bounds__(256) void k_binA(const int* __restrict__ src,
                                              const int* __restrict__ dst,
                                              const unsigned* __restrict__ binOff,
                                              unsigned* __restrict__ binPos,
                                              unsigned* __restrict__ packed) {
    int e = blockIdx.x * 1024 + threadIdx.x;     // 3125 * 1024 == E exactly
#pragma unroll
    for (int i = 0; i < 4; ++i, e += 256) {
        unsigned s = (unsigned)src[e];
        unsigned d = (unsigned)dst[e];
        unsigned bin = d >> 6;
        unsigned pos = atomicAdd(&binPos[bin], 1u);
        packed[binOff[bin] + pos] = ((d & 63u) << 17) | s;
    }
}

// ---------------- per-bin degree -> dinv ----------------
__global__ __launch_bounds__(256) void k_degdinv(const unsigned* __restrict__ binOff,
                                                 const unsigned* __restrict__ binCnt,
                                                 const unsigned* __restrict__ packed,
                                                 float* __restrict__ dinv) {
    __shared__ unsigned cnt[64];
    int bin = blockIdx.x;
    if (threadIdx.x < 64) cnt[threadIdx.x] = 0;
    __syncthreads();
    unsigned base = binOff[bin], len = binCnt[bin];
    for (unsigned j = threadIdx.x; j < len; j += 256)
        atomicAdd(&cnt[packed[base + j] >> 17], 1u);
    __syncthreads();
    if (threadIdx.x < 64) {
        int node = bin * 64 + (int)threadIdx.x;
        if (node < N_NODES) dinv[node] = rsqrtf((float)cnt[threadIdx.x] + 1.0f);
    }
}

// ---------------- GEMM1: xw = (x @ W1) * dinv[row] ----------------
#define TM 128
#define TK 32
__global__ __launch_bounds__(256) void k_gemm1(const float* __restrict__ x,
                                               const float* __restrict__ W1,
                                               const float* __restrict__ dinv,
                                               float* __restrict__ xw) {
    __shared__ float xs[TM * TK];   // quad-swizzled
    __shared__ float ws[TK * H_F];
    const int t   = threadIdx.x;
    const int tr  = t >> 3;
    const int tq  = t & 7;
    const int c0  = tq * 4;
    const int swz = tr & 7;
    const int row0 = blockIdx.x * TM;
    float acc[4][4] = {};
    for (int k0 = 0; k0 < IN_F; k0 += TK) {
#pragma unroll
        for (int p = 0; p < 4; ++p) {
            int r = p * 32 + tr;
            int gr = row0 + r;
            if (gr >= N_NODES) gr = N_NODES - 1;
            float4 v = *(const float4*)(x + (size_t)gr * IN_F + k0 + tq * 4);
            *(float4*)&xs[r * TK + ((tq ^ (r & 7)) << 2)] = v;
        }
        {
            float4 v = *(const float4*)(W1 + (size_t)(k0 + tr) * H_F + tq * 4);
            *(float4*)&ws[tr * H_F + tq * 4] = v;
        }
        __syncthreads();
#pragma unroll
        for (int kk = 0; kk < TK; kk += 4) {
            float xr[4][4], wr[4][4];
            const int q = ((kk >> 2) ^ swz) << 2;
#pragma unroll
            for (int i = 0; i < 4; ++i) {
                float4 v = *(const float4*)&xs[(tr + 32 * i) * TK + q];
                xr[i][0] = v.x; xr[i][1] = v.y; xr[i][2] = v.z; xr[i][3] = v.w;
            }
#pragma unroll
            for (int j = 0; j < 4; ++j) {
                float4 v = *(const float4*)&ws[(kk + j) * H_F + c0];
                wr[j][0] = v.x; wr[j][1] = v.y; wr[j][2] = v.z; wr[j][3] = v.w;
            }
#pragma unroll
            for (int k = 0; k < 4; ++k)
#pragma unroll
                for (int i = 0; i < 4; ++i)
#pragma unroll
                    for (int j = 0; j < 4; ++j)
                        acc[i][j] = fmaf(xr[i][k], wr[k][j], acc[i][j]);
        }
        __syncthreads();
    }
#pragma unroll
    for (int i = 0; i < 4; ++i) {
        int r = row0 + tr + 32 * i;
        if (r < N_NODES) {
            float dv = dinv[r];
            float4 o = make_float4(acc[i][0] * dv, acc[i][1] * dv, acc[i][2] * dv, acc[i][3] * dv);
            *(float4*)(xw + (size_t)r * H_F + c0) = o;
        }
    }
}

// ---------------- gather1: per-bin LDS accumulation + BN/ReLU epilogue ----------------
__global__ __launch_bounds__(256) void k_gather1(const unsigned* __restrict__ binOff,
                                                 const unsigned* __restrict__ binCnt,
                                                 const unsigned* __restrict__ packed,
                                                 const float* __restrict__ xw,
                                                 const float* __restrict__ dinv,
                                                 const float* __restrict__ scale,
                                                 const float* __restrict__ shift,
                                                 float* __restrict__ hs) {
    __shared__ float acc[64 * H_F];
    __shared__ float sc[H_F], sh[H_F];
    if (threadIdx.x < H_F) { sc[threadIdx.x] = scale[threadIdx.x]; sh[threadIdx.x] = shift[threadIdx.x]; }
    for (int i = threadIdx.x; i < 64 * H_F; i += 256) acc[i] = 0.f;
    __syncthreads();
    int bin = blockIdx.x;
    unsigned base = binOff[bin], len = binCnt[bin];
    int r0 = threadIdx.x & 7;
    for (unsigned j = threadIdx.x; j < len; j += 256) {
        unsigned p = packed[base + j];
        const float* row = xw + (size_t)(p & 0x1FFFFu) * H_F;
        float* arow = acc + (p >> 17) * H_F;
        float4 v[8];
#pragma unroll
        for (int i = 0; i < 8; ++i) v[i] = *(const float4*)(row + (((r0 + i) & 7) << 2));
#pragma unroll
        for (int i = 0; i < 8; ++i) {
            int q = ((r0 + i) & 7) << 2;
            atomicAdd(&arow[q + 0], v[i].x);
            atomicAdd(&arow[q + 1], v[i].y);
            atomicAdd(&arow[q + 2], v[i].z);
            atomicAdd(&arow[q + 3], v[i].w);
        }
    }
    __syncthreads();
    size_t bb = (size_t)bin * (64 * H_F);
#pragma unroll
    for (int p = 0; p < 8; ++p) {
        int flat = p * 256 + (int)threadIdx.x;
        int node = bin * 64 + (flat >> 5);
        if (node < N_NODES) {
            int c = flat & 31;
            float dv = dinv[node];
            float a = (acc[flat] + xw[bb + flat]) * dv;   // + self-loop
            hs[bb + flat] = fmaxf(fmaf(a, sc[c], sh[c]), 0.f) * dv;
        }
    }
}

// ---------------- gather2 + out GEMM: out = ((A·hs + hs)[d]*dinv) @ W2 + b2 ----------------
__global__ __launch_bounds__(256) void k_gather2(const unsigned* __restrict__ binOff,
                                                 const unsigned* __restrict__ binCnt,
                                                 const unsigned* __restrict__ packed,
                                                 const float* __restrict__ hs,
                                                 const float* __restrict__ dinv,
                                                 const float* __restrict__ W2,
                                                 const float* __restrict__ b2,
                                                 float* __restrict__ out) {
    __shared__ float acc[64 * H_F];   // 8 KB
    __shared__ float w[H_F * OUT_F];  // 8 KB
    __shared__ float bs[OUT_F];
    for (int i = threadIdx.x; i < 64 * H_F; i += 256) { acc[i] = 0.f; w[i] = W2[i]; }
    if (threadIdx.x < OUT_F) bs[threadIdx.x] = b2[threadIdx.x];
    __syncthreads();
    int bin = blockIdx.x;
    unsigned base = binOff[bin], len = binCnt[bin];
    int r0 = threadIdx.x & 7;
    for (unsigned j = threadIdx.x; j < len; j += 256) {
        unsigned p = packed[base + j];
        const float* row = hs + (size_t)(p & 0x1FFFFu) * H_F;
        float* arow = acc + (p >> 17) * H_F;
        float4 v[8];
#pragma unroll
        for (int i = 0; i < 8; ++i) v[i] = *(const float4*)(row + (((r0 + i) & 7) << 2));
#pragma unroll
        for (int i = 0; i < 8; ++i) {
            int q = ((r0 + i) & 7) << 2;
            atomicAdd(&arow[q + 0], v[i].x);
            atomicAdd(&arow[q + 1], v[i].y);
            atomicAdd(&arow[q + 2], v[i].z);
            atomicAdd(&arow[q + 3], v[i].w);
        }
    }
    __syncthreads();
    size_t bb = (size_t)bin * (64 * H_F);
#pragma unroll
    for (int p = 0; p < 8; ++p) {
        int flat = p * 256 + (int)threadIdx.x;
        int node = bin * 64 + (flat >> 5);
        if (node < N_NODES)
            acc[flat] = (acc[flat] + hs[bb + flat]) * dinv[node];
    }
    __syncthreads();
    int lane = threadIdx.x & 63;
    int wv = threadIdx.x >> 6;
#pragma unroll
    for (int i = 0; i < 16; ++i) {
        int n = wv * 16 + i;
        int node = bin * 64 + n;
        if (node < N_NODES) {
            float o = bs[lane];
            const float* ar = acc + n * H_F;
#pragma unroll
            for (int kk = 0; kk < H_F; ++kk)
                o = fmaf(ar[kk], w[kk * OUT_F + lane], o);
            out[(size_t)node * OUT_F + lane] = o;
        }
    }
}

extern "C" void kernel_launch(void* const* d_in, const int* in_sizes, int n_in,
                              void* d_out, int out_size, void* d_ws, size_t ws_size,
                              hipStream_t stream) {
    const float* x     = (const float*)d_in[0];
    const int*   ei    = (const int*)d_in[1];
    const float* W1    = (const float*)d_in[2];
    const float* b1    = (const float*)d_in[3];
    const float* W2    = (const float*)d_in[4];
    const float* b2    = (const float*)d_in[5];
    const float* gamma = (const float*)d_in[6];
    const float* beta  = (const float*)d_in[7];
    const float* rm    = (const float*)d_in[8];
    const float* rv    = (const float*)d_in[9];
    float* out = (float*)d_out;

    const int* src = ei;
    const int* dst = ei + E_EDGES;

    // workspace layout (~38.9 MB total)
    float*    xw     = (float*)d_ws;                    // N*32
    float*    hs     = xw + (size_t)N_NODES * H_F;      // N*32
    float*    dinv   = hs + (size_t)N_NODES * H_F;      // N
    float*    scale  = dinv + N_NODES;                  // 32
    float*    shift  = scale + H_F;                     // 32
    unsigned* binCnt = (unsigned*)(shift + H_F);        // NBINS
    unsigned* binOff = binCnt + NBINS;                  // NBINS
    unsigned* binPos = binOff + NBINS;                  // NBINS
    unsigned* packed = binPos + NBINS;                  // E

    hipMemsetAsync(binCnt, 0, (size_t)3 * NBINS * sizeof(unsigned), stream);

    k_hist<<<512, 256, 0, stream>>>(dst, binCnt);
    k_scanbins<<<1, 256, 0, stream>>>(binCnt, binOff);
    k_binA<<<E_EDGES / 1024, 256, 0, stream>>>(src, dst, binOff, binPos, packed);
    k_degdinv<<<NBINS, 256, 0, stream>>>(binOff, binCnt, packed, dinv);
    k_scales<<<1, 64, 0, stream>>>(gamma, beta, rm, rv, b1, scale, shift);

    k_gemm1<<<(N_NODES + TM - 1) / TM, 256, 0, stream>>>(x, W1, dinv, xw);
    k_gather1<<<NBINS, 256, 0, stream>>>(binOff, binCnt, packed, xw, dinv, scale, shift, hs);
    k_gather2<<<NBINS, 256, 0, stream>>>(binOff, binCnt, packed, hs, dinv, W2, b2, out);
}

// Round 5
// 389.428 us; speedup vs baseline: 6.2576x; 6.2576x over previous
//
#include <hip/hip_runtime.h>

#define N_NODES 100000
#define E_EDGES 3200000
#define IN_F 512
#define H_F 32
#define OUT_F 64
#define BN_EPS 1e-5f
#define NBINS 1563              // ceil(100000 / 64), 64 nodes per bin
#define CHUNK 16384             // edges per binfill block

// ---------------- BN fold ----------------
__global__ void k_scales(const float* __restrict__ gamma, const float* __restrict__ beta,
                         const float* __restrict__ rm, const float* __restrict__ rv,
                         const float* __restrict__ b1,
                         float* __restrict__ scale, float* __restrict__ shift) {
    int k = threadIdx.x;
    if (k < H_F) {
        float s = gamma[k] * rsqrtf(rv[k] + BN_EPS);
        scale[k] = s;
        shift[k] = (b1[k] - rm[k]) * s + beta[k];
    }
}

// ---------------- bin histogram (LDS-privatized) ----------------
__global__ __launch_bounds__(256) void k_hist(const int* __restrict__ dst,
                                              unsigned* __restrict__ binCnt) {
    __shared__ unsigned h[NBINS];
    for (int i = threadIdx.x; i < NBINS; i += 256) h[i] = 0;
    __syncthreads();
    for (int e = blockIdx.x * 256 + threadIdx.x; e < E_EDGES; e += 256 * 512)
        atomicAdd(&h[((unsigned)dst[e]) >> 6], 1u);
    __syncthreads();
    for (int i = threadIdx.x; i < NBINS; i += 256) {
        unsigned v = h[i];
        if (v) atomicAdd(&binCnt[i], v);
    }
}

// ---------------- exclusive scan over 1563 bins (1 block) ----------------
__global__ __launch_bounds__(256) void k_scanbins(const unsigned* __restrict__ binCnt,
                                                  unsigned* __restrict__ binOff) {
    __shared__ unsigned carry;
    __shared__ unsigned wtot[4];
    if (threadIdx.x == 0) carry = 0;
    __syncthreads();
    int lane = threadIdx.x & 63, wid = threadIdx.x >> 6;
    for (int base = 0; base < NBINS; base += 256) {
        int i = base + (int)threadIdx.x;
        unsigned v = (i < NBINS) ? binCnt[i] : 0u;
        unsigned xs = v;
#pragma unroll
        for (int s = 1; s < 64; s <<= 1) {
            unsigned t = __shfl_up(xs, s, 64);
            if (lane >= s) xs += t;
        }
        if (lane == 63) wtot[wid] = xs;
        __syncthreads();
        unsigned wbase = 0, tot = 0;
#pragma unroll
        for (int w = 0; w < 4; ++w) { if (w < wid) wbase += wtot[w]; tot += wtot[w]; }
        if (i < NBINS) binOff[i] = carry + wbase + xs - v;
        __syncthreads();
        if (threadIdx.x == 0) carry += tot;
        __syncthreads();
    }
}

// ---------------- bin fill with per-block range reservation ----------------
// pass A: LDS histogram of chunk; reserve: ONE global atomic per non-empty bin;
// pass B: LDS bump-allocate, write packed = (d_local<<17) | src.
__global__ __launch_bounds__(256) void k_binfill(const int* __restrict__ src,
                                                 const int* __restrict__ dst,
                                                 const unsigned* __restrict__ binOff,
                                                 unsigned* __restrict__ binPos,
                                                 unsigned* __restrict__ packed) {
    __shared__ unsigned h[NBINS];
    for (int i = threadIdx.x; i < NBINS; i += 256) h[i] = 0;
    __syncthreads();
    int e0 = blockIdx.x * CHUNK;
    int e1 = min(e0 + CHUNK, E_EDGES);
    for (int e = e0 + threadIdx.x; e < e1; e += 256)
        atomicAdd(&h[((unsigned)dst[e]) >> 6], 1u);
    __syncthreads();
    for (int i = threadIdx.x; i < NBINS; i += 256) {
        unsigned c = h[i];
        h[i] = c ? atomicAdd(&binPos[i], c) : 0u;   // reserved base (bin-relative)
    }
    __syncthreads();
    for (int e = e0 + threadIdx.x; e < e1; e += 256) {
        unsigned s = (unsigned)src[e];
        unsigned d = (unsigned)dst[e];
        unsigned bin = d >> 6;
        unsigned pos = atomicAdd(&h[bin], 1u);      // LDS bump within reserved range
        packed[binOff[bin] + pos] = ((d & 63u) << 17) | s;
    }
}

// ---------------- per-bin sort to per-node CSR + deg/dinv/off ----------------
__global__ __launch_bounds__(256) void k_sortbin(const unsigned* __restrict__ binOff,
                                                 const unsigned* __restrict__ binCnt,
                                                 const unsigned* __restrict__ packed,
                                                 unsigned* __restrict__ off,
                                                 unsigned* __restrict__ deg,
                                                 float* __restrict__ dinv,
                                                 unsigned* __restrict__ csr) {
    __shared__ unsigned cnt[64];
    __shared__ unsigned cur[64];
    int bin = blockIdx.x;
    if (threadIdx.x < 64) cnt[threadIdx.x] = 0;
    __syncthreads();
    unsigned base = binOff[bin], len = binCnt[bin];
    for (unsigned j = threadIdx.x; j < len; j += 256)
        atomicAdd(&cnt[packed[base + j] >> 17], 1u);
    __syncthreads();
    if (threadIdx.x < 64) {   // wave 0: exclusive scan over the 64 local nodes
        unsigned v = cnt[threadIdx.x];
        unsigned xs = v;
#pragma unroll
        for (int s = 1; s < 64; s <<= 1) {
            unsigned t = __shfl_up(xs, s, 64);
            if ((int)threadIdx.x >= s) xs += t;
        }
        unsigned loc = xs - v;
        cur[threadIdx.x] = loc;
        int node = bin * 64 + (int)threadIdx.x;
        if (node < N_NODES) {
            off[node]  = base + loc;
            deg[node]  = v;
            dinv[node] = rsqrtf((float)v + 1.0f);   // +1 self-loop
        }
    }
    __syncthreads();
    for (unsigned j = threadIdx.x; j < len; j += 256) {
        unsigned p = packed[base + j];
        unsigned pos = atomicAdd(&cur[p >> 17], 1u);
        csr[base + pos] = p & 0x1FFFFu;             // global src index
    }
}

// ---------------- GEMM1: xw = (x @ W1) * dinv[row]  ([N,512]x[512,32]) ----------------
#define TM 128
#define TK 32
__global__ __launch_bounds__(256) void k_gemm1(const float* __restrict__ x,
                                               const float* __restrict__ W1,
                                               const float* __restrict__ dinv,
                                               float* __restrict__ xw) {
    __shared__ float xs[TM * TK];   // quad-swizzled
    __shared__ float ws[TK * H_F];
    const int t   = threadIdx.x;
    const int tr  = t >> 3;
    const int tq  = t & 7;
    const int c0  = tq * 4;
    const int swz = tr & 7;
    const int row0 = blockIdx.x * TM;
    float acc[4][4] = {};
    for (int k0 = 0; k0 < IN_F; k0 += TK) {
#pragma unroll
        for (int p = 0; p < 4; ++p) {
            int r = p * 32 + tr;
            int gr = row0 + r;
            if (gr >= N_NODES) gr = N_NODES - 1;
            float4 v = *(const float4*)(x + (size_t)gr * IN_F + k0 + tq * 4);
            *(float4*)&xs[r * TK + ((tq ^ (r & 7)) << 2)] = v;
        }
        {
            float4 v = *(const float4*)(W1 + (size_t)(k0 + tr) * H_F + tq * 4);
            *(float4*)&ws[tr * H_F + tq * 4] = v;
        }
        __syncthreads();
#pragma unroll
        for (int kk = 0; kk < TK; kk += 4) {
            float xr[4][4], wr[4][4];
            const int q = ((kk >> 2) ^ swz) << 2;
#pragma unroll
            for (int i = 0; i < 4; ++i) {
                float4 v = *(const float4*)&xs[(tr + 32 * i) * TK + q];
                xr[i][0] = v.x; xr[i][1] = v.y; xr[i][2] = v.z; xr[i][3] = v.w;
            }
#pragma unroll
            for (int j = 0; j < 4; ++j) {
                float4 v = *(const float4*)&ws[(kk + j) * H_F + c0];
                wr[j][0] = v.x; wr[j][1] = v.y; wr[j][2] = v.z; wr[j][3] = v.w;
            }
#pragma unroll
            for (int k = 0; k < 4; ++k)
#pragma unroll
                for (int i = 0; i < 4; ++i)
#pragma unroll
                    for (int j = 0; j < 4; ++j)
                        acc[i][j] = fmaf(xr[i][k], wr[k][j], acc[i][j]);
        }
        __syncthreads();
    }
#pragma unroll
    for (int i = 0; i < 4; ++i) {
        int r = row0 + tr + 32 * i;
        if (r < N_NODES) {
            float dv = dinv[r];
            float4 o = make_float4(acc[i][0] * dv, acc[i][1] * dv, acc[i][2] * dv, acc[i][3] * dv);
            *(float4*)(xw + (size_t)r * H_F + c0) = o;
        }
    }
}

// ---------------- gather1: hs[d] = relu(bn((sum_in xw[s] + xw[d]) * dinv[d])) * dinv[d] ----------------
// one wave per node: 8 edge-groups x 8 lanes x float4, register accumulation (no atomics)
__global__ __launch_bounds__(256) void k_gather1(const unsigned* __restrict__ off,
                                                 const unsigned* __restrict__ deg,
                                                 const unsigned* __restrict__ csr,
                                                 const float* __restrict__ xw,
                                                 const float* __restrict__ dinv,
                                                 const float* __restrict__ scale,
                                                 const float* __restrict__ shift,
                                                 float* __restrict__ hs) {
    int wid  = threadIdx.x >> 6;
    int lane = threadIdx.x & 63;
    int g    = lane >> 3;
    int q    = lane & 7;
    int d = blockIdx.x * 4 + wid;                    // N = 4*25000 exactly
    unsigned beg = off[d];
    unsigned end = beg + deg[d];
    float4 acc = make_float4(0.f, 0.f, 0.f, 0.f);
    for (unsigned j = beg + (unsigned)g; j < end; j += 8) {
        unsigned s = csr[j];
        float4 v = *(const float4*)(xw + (size_t)s * H_F + q * 4);
        acc.x += v.x; acc.y += v.y; acc.z += v.z; acc.w += v.w;
    }
#pragma unroll
    for (int st = 8; st < 64; st <<= 1) {
        acc.x += __shfl_xor(acc.x, st, 64);
        acc.y += __shfl_xor(acc.y, st, 64);
        acc.z += __shfl_xor(acc.z, st, 64);
        acc.w += __shfl_xor(acc.w, st, 64);
    }
    if (g == 0) {
        float dv = dinv[d];
        float4 sv = *(const float4*)(xw + (size_t)d * H_F + q * 4);   // self-loop
        float4 sc = *(const float4*)(scale + q * 4);
        float4 sh = *(const float4*)(shift + q * 4);
        float4 h;
        h.x = fmaxf(fmaf((acc.x + sv.x) * dv, sc.x, sh.x), 0.f) * dv;
        h.y = fmaxf(fmaf((acc.y + sv.y) * dv, sc.y, sh.y), 0.f) * dv;
        h.z = fmaxf(fmaf((acc.z + sv.z) * dv, sc.z, sh.z), 0.f) * dv;
        h.w = fmaxf(fmaf((acc.w + sv.w) * dv, sc.w, sh.w), 0.f) * dv;
        *(float4*)(hs + (size_t)d * H_F + q * 4) = h;
    }
}

// ---------------- gather2 + out-GEMM fused: out[d] = ((sum_in hs[s] + hs[d])*dinv[d]) @ W2 + b2 ----------------
__global__ __launch_bounds__(256) void k_gather2(const unsigned* __restrict__ off,
                                                 const unsigned* __restrict__ deg,
                                                 const unsigned* __restrict__ csr,
                                                 const float* __restrict__ hs,
                                                 const float* __restrict__ dinv,
                                                 const float* __restrict__ W2,
                                                 const float* __restrict__ b2,
                                                 float* __restrict__ out) {
    __shared__ float ws[H_F * OUT_F];   // 8 KB
    __shared__ float bs[OUT_F];
    for (int i = threadIdx.x; i < H_F * OUT_F; i += 256) ws[i] = W2[i];
    if (threadIdx.x < OUT_F) bs[threadIdx.x] = b2[threadIdx.x];
    __syncthreads();
    int wid  = threadIdx.x >> 6;
    int lane = threadIdx.x & 63;
    int g    = lane >> 3;
    int q    = lane & 7;
    int d = blockIdx.x * 4 + wid;
    unsigned beg = off[d];
    unsigned end = beg + deg[d];
    float4 acc = make_float4(0.f, 0.f, 0.f, 0.f);
    for (unsigned j = beg + (unsigned)g; j < end; j += 8) {
        unsigned s = csr[j];
        float4 v = *(const float4*)(hs + (size_t)s * H_F + q * 4);
        acc.x += v.x; acc.y += v.y; acc.z += v.z; acc.w += v.w;
    }
#pragma unroll
    for (int st = 8; st < 64; st <<= 1) {
        acc.x += __shfl_xor(acc.x, st, 64);
        acc.y += __shfl_xor(acc.y, st, 64);
        acc.z += __shfl_xor(acc.z, st, 64);
        acc.w += __shfl_xor(acc.w, st, 64);
    }
    float dv = dinv[d];
    float4 sv = *(const float4*)(hs + (size_t)d * H_F + q * 4);       // self-loop
    float tv[4];
    tv[0] = (acc.x + sv.x) * dv;
    tv[1] = (acc.y + sv.y) * dv;
    tv[2] = (acc.z + sv.z) * dv;
    tv[3] = (acc.w + sv.w) * dv;
    float o = bs[lane];
#pragma unroll
    for (int k = 0; k < H_F; ++k) {
        float a = __shfl(tv[k & 3], k >> 2, 8);
        o = fmaf(a, ws[k * OUT_F + lane], o);
    }
    out[(size_t)d * OUT_F + lane] = o;
}

extern "C" void kernel_launch(void* const* d_in, const int* in_sizes, int n_in,
                              void* d_out, int out_size, void* d_ws, size_t ws_size,
                              hipStream_t stream) {
    const float* x     = (const float*)d_in[0];
    const int*   ei    = (const int*)d_in[1];
    const float* W1    = (const float*)d_in[2];
    const float* b1    = (const float*)d_in[3];
    const float* W2    = (const float*)d_in[4];
    const float* b2    = (const float*)d_in[5];
    const float* gamma = (const float*)d_in[6];
    const float* beta  = (const float*)d_in[7];
    const float* rm    = (const float*)d_in[8];
    const float* rv    = (const float*)d_in[9];
    float* out = (float*)d_out;

    const int* src = ei;
    const int* dst = ei + E_EDGES;

    // workspace layout (~40 MB). NOTE: packed aliases hs — lifetimes disjoint
    // (packed: binfill..sortbin; hs: gather1..gather2).
    float*    xw     = (float*)d_ws;                    // N*32
    float*    hs     = xw + (size_t)N_NODES * H_F;      // N*32  (alias: packed)
    unsigned* packed = (unsigned*)hs;                   // E  (E == N*32)
    unsigned* csr    = (unsigned*)(hs + (size_t)N_NODES * H_F);  // E
    float*    dinv   = (float*)(csr + E_EDGES);         // N
    unsigned* off    = (unsigned*)(dinv + N_NODES);     // N
    unsigned* deg    = off + N_NODES;                   // N
    float*    scale  = (float*)(deg + N_NODES);         // 32
    float*    shift  = scale + H_F;                     // 32
    unsigned* binCnt = (unsigned*)(shift + H_F);        // NBINS
    unsigned* binPos = binCnt + NBINS;                  // NBINS
    unsigned* binOff = binPos + NBINS;                  // NBINS

    hipMemsetAsync(binCnt, 0, (size_t)2 * NBINS * sizeof(unsigned), stream);

    k_hist<<<512, 256, 0, stream>>>(dst, binCnt);
    k_scanbins<<<1, 256, 0, stream>>>(binCnt, binOff);
    k_binfill<<<(E_EDGES + CHUNK - 1) / CHUNK, 256, 0, stream>>>(src, dst, binOff, binPos, packed);
    k_sortbin<<<NBINS, 256, 0, stream>>>(binOff, binCnt, packed, off, deg, dinv, csr);
    k_scales<<<1, 64, 0, stream>>>(gamma, beta, rm, rv, b1, scale, shift);

    k_gemm1<<<(N_NODES + TM - 1) / TM, 256, 0, stream>>>(x, W1, dinv, xw);
    k_gather1<<<N_NODES / 4, 256, 0, stream>>>(off, deg, csr, xw, dinv, scale, shift, hs);
    k_gather2<<<N_NODES / 4, 256, 0, stream>>>(off, deg, csr, hs, dinv, W2, b2, out);
}

// Round 6
// 364.273 us; speedup vs baseline: 6.6897x; 1.0691x over previous
//
#include <hip/hip_runtime.h>

#define N_NODES 100000
#define E_EDGES 3200000
#define IN_F 512
#define H_F 32
#define OUT_F 64
#define BN_EPS 1e-5f
#define NBINS 1563              // ceil(100000 / 64), 64 nodes per bin
#define CHUNK 16384             // edges per binfill block

// ---------------- prep: zero bin counters + BN fold (replaces memset + k_scales) ----------------
__global__ __launch_bounds__(256) void k_prep(const float* __restrict__ gamma,
                                              const float* __restrict__ beta,
                                              const float* __restrict__ rm,
                                              const float* __restrict__ rv,
                                              const float* __restrict__ b1,
                                              float* __restrict__ scale,
                                              float* __restrict__ shift,
                                              unsigned* __restrict__ binCnt,
                                              unsigned* __restrict__ binPos) {
    int t = blockIdx.x * 256 + threadIdx.x;
    if (t < NBINS) { binCnt[t] = 0u; binPos[t] = 0u; }
    if (blockIdx.x == 0 && threadIdx.x < H_F) {
        int k = threadIdx.x;
        float s = gamma[k] * rsqrtf(rv[k] + BN_EPS);
        scale[k] = s;
        shift[k] = (b1[k] - rm[k]) * s + beta[k];
    }
}

// ---------------- bin histogram (LDS-privatized) ----------------
__global__ __launch_bounds__(256) void k_hist(const int* __restrict__ dst,
                                              unsigned* __restrict__ binCnt) {
    __shared__ unsigned h[NBINS];
    for (int i = threadIdx.x; i < NBINS; i += 256) h[i] = 0;
    __syncthreads();
    for (int e = blockIdx.x * 256 + threadIdx.x; e < E_EDGES; e += 256 * 512)
        atomicAdd(&h[((unsigned)dst[e]) >> 6], 1u);
    __syncthreads();
    for (int i = threadIdx.x; i < NBINS; i += 256) {
        unsigned v = h[i];
        if (v) atomicAdd(&binCnt[i], v);
    }
}

// ---------------- exclusive scan over 1563 bins (1 block) ----------------
__global__ __launch_bounds__(256) void k_scanbins(const unsigned* __restrict__ binCnt,
                                                  unsigned* __restrict__ binOff) {
    __shared__ unsigned carry;
    __shared__ unsigned wtot[4];
    if (threadIdx.x == 0) carry = 0;
    __syncthreads();
    int lane = threadIdx.x & 63, wid = threadIdx.x >> 6;
    for (int base = 0; base < NBINS; base += 256) {
        int i = base + (int)threadIdx.x;
        unsigned v = (i < NBINS) ? binCnt[i] : 0u;
        unsigned xs = v;
#pragma unroll
        for (int s = 1; s < 64; s <<= 1) {
            unsigned t = __shfl_up(xs, s, 64);
            if (lane >= s) xs += t;
        }
        if (lane == 63) wtot[wid] = xs;
        __syncthreads();
        unsigned wbase = 0, tot = 0;
#pragma unroll
        for (int w = 0; w < 4; ++w) { if (w < wid) wbase += wtot[w]; tot += wtot[w]; }
        if (i < NBINS) binOff[i] = carry + wbase + xs - v;
        __syncthreads();
        if (threadIdx.x == 0) carry += tot;
        __syncthreads();
    }
}

// ---------------- bin fill with per-block range reservation ----------------
__global__ __launch_bounds__(256) void k_binfill(const int* __restrict__ src,
                                                 const int* __restrict__ dst,
                                                 const unsigned* __restrict__ binOff,
                                                 unsigned* __restrict__ binPos,
                                                 unsigned* __restrict__ packed) {
    __shared__ unsigned h[NBINS];
    for (int i = threadIdx.x; i < NBINS; i += 256) h[i] = 0;
    __syncthreads();
    int e0 = blockIdx.x * CHUNK;
    int e1 = min(e0 + CHUNK, E_EDGES);
    for (int e = e0 + threadIdx.x; e < e1; e += 256)
        atomicAdd(&h[((unsigned)dst[e]) >> 6], 1u);
    __syncthreads();
    for (int i = threadIdx.x; i < NBINS; i += 256) {
        unsigned c = h[i];
        h[i] = c ? atomicAdd(&binPos[i], c) : 0u;   // reserved base (bin-relative)
    }
    __syncthreads();
    for (int e = e0 + threadIdx.x; e < e1; e += 256) {
        unsigned s = (unsigned)src[e];
        unsigned d = (unsigned)dst[e];
        unsigned bin = d >> 6;
        unsigned pos = atomicAdd(&h[bin], 1u);      // LDS bump within reserved range
        packed[binOff[bin] + pos] = ((d & 63u) << 17) | s;
    }
}

// ---------------- per-bin sort to per-node CSR + deg/dinv/off ----------------
__global__ __launch_bounds__(256) void k_sortbin(const unsigned* __restrict__ binOff,
                                                 const unsigned* __restrict__ binCnt,
                                                 const unsigned* __restrict__ packed,
                                                 unsigned* __restrict__ off,
                                                 unsigned* __restrict__ deg,
                                                 float* __restrict__ dinv,
                                                 unsigned* __restrict__ csr) {
    __shared__ unsigned cnt[64];
    __shared__ unsigned cur[64];
    int bin = blockIdx.x;
    if (threadIdx.x < 64) cnt[threadIdx.x] = 0;
    __syncthreads();
    unsigned base = binOff[bin], len = binCnt[bin];
    for (unsigned j = threadIdx.x; j < len; j += 256)
        atomicAdd(&cnt[packed[base + j] >> 17], 1u);
    __syncthreads();
    if (threadIdx.x < 64) {   // wave 0: exclusive scan over the 64 local nodes
        unsigned v = cnt[threadIdx.x];
        unsigned xs = v;
#pragma unroll
        for (int s = 1; s < 64; s <<= 1) {
            unsigned t = __shfl_up(xs, s, 64);
            if ((int)threadIdx.x >= s) xs += t;
        }
        unsigned loc = xs - v;
        cur[threadIdx.x] = loc;
        int node = bin * 64 + (int)threadIdx.x;
        if (node < N_NODES) {
            off[node]  = base + loc;
            deg[node]  = v;
            dinv[node] = rsqrtf((float)v + 1.0f);   // +1 self-loop
        }
    }
    __syncthreads();
    for (unsigned j = threadIdx.x; j < len; j += 256) {
        unsigned p = packed[base + j];
        unsigned pos = atomicAdd(&cur[p >> 17], 1u);
        csr[base + pos] = p & 0x1FFFFu;             // global src index
    }
}

// ---------------- GEMM1: xw = (x @ W1) * dinv[row]  ([N,512]x[512,32]) ----------------
#define TM 128
#define TK 32
__global__ __launch_bounds__(256) void k_gemm1(const float* __restrict__ x,
                                               const float* __restrict__ W1,
                                               const float* __restrict__ dinv,
                                               float* __restrict__ xw) {
    __shared__ float xs[TM * TK];   // quad-swizzled
    __shared__ float ws[TK * H_F];
    const int t   = threadIdx.x;
    const int tr  = t >> 3;
    const int tq  = t & 7;
    const int c0  = tq * 4;
    const int swz = tr & 7;
    const int row0 = blockIdx.x * TM;
    float acc[4][4] = {};
    for (int k0 = 0; k0 < IN_F; k0 += TK) {
#pragma unroll
        for (int p = 0; p < 4; ++p) {
            int r = p * 32 + tr;
            int gr = row0 + r;
            if (gr >= N_NODES) gr = N_NODES - 1;
            float4 v = *(const float4*)(x + (size_t)gr * IN_F + k0 + tq * 4);
            *(float4*)&xs[r * TK + ((tq ^ (r & 7)) << 2)] = v;
        }
        {
            float4 v = *(const float4*)(W1 + (size_t)(k0 + tr) * H_F + tq * 4);
            *(float4*)&ws[tr * H_F + tq * 4] = v;
        }
        __syncthreads();
#pragma unroll
        for (int kk = 0; kk < TK; kk += 4) {
            float xr[4][4], wr[4][4];
            const int q = ((kk >> 2) ^ swz) << 2;
#pragma unroll
            for (int i = 0; i < 4; ++i) {
                float4 v = *(const float4*)&xs[(tr + 32 * i) * TK + q];
                xr[i][0] = v.x; xr[i][1] = v.y; xr[i][2] = v.z; xr[i][3] = v.w;
            }
#pragma unroll
            for (int j = 0; j < 4; ++j) {
                float4 v = *(const float4*)&ws[(kk + j) * H_F + c0];
                wr[j][0] = v.x; wr[j][1] = v.y; wr[j][2] = v.z; wr[j][3] = v.w;
            }
#pragma unroll
            for (int k = 0; k < 4; ++k)
#pragma unroll
                for (int i = 0; i < 4; ++i)
#pragma unroll
                    for (int j = 0; j < 4; ++j)
                        acc[i][j] = fmaf(xr[i][k], wr[k][j], acc[i][j]);
        }
        __syncthreads();
    }
#pragma unroll
    for (int i = 0; i < 4; ++i) {
        int r = row0 + tr + 32 * i;
        if (r < N_NODES) {
            float dv = dinv[r];
            float4 o = make_float4(acc[i][0] * dv, acc[i][1] * dv, acc[i][2] * dv, acc[i][3] * dv);
            *(float4*)(xw + (size_t)r * H_F + c0) = o;
        }
    }
}

// ---------------- gather1: software-pipelined (4 rows in flight per 8-lane group) ----------------
__global__ __launch_bounds__(256) void k_gather1(const unsigned* __restrict__ off,
                                                 const unsigned* __restrict__ deg,
                                                 const unsigned* __restrict__ csr,
                                                 const float* __restrict__ xw,
                                                 const float* __restrict__ dinv,
                                                 const float* __restrict__ scale,
                                                 const float* __restrict__ shift,
                                                 float* __restrict__ hs) {
    int wid  = threadIdx.x >> 6;
    int lane = threadIdx.x & 63;
    int g    = lane >> 3;
    int q    = lane & 7;
    int d = blockIdx.x * 4 + wid;                    // N = 4*25000 exactly
    const unsigned* cp = csr + off[d];
    unsigned n = deg[d];
    float4 acc = make_float4(0.f, 0.f, 0.f, 0.f);
    unsigned i = g;
    for (; i + 24 < n; i += 32) {                    // 4 edges per group per iter
        unsigned s0 = cp[i], s1 = cp[i + 8], s2 = cp[i + 16], s3 = cp[i + 24];
        float4 v0 = *(const float4*)(xw + (size_t)s0 * H_F + q * 4);
        float4 v1 = *(const float4*)(xw + (size_t)s1 * H_F + q * 4);
        float4 v2 = *(const float4*)(xw + (size_t)s2 * H_F + q * 4);
        float4 v3 = *(const float4*)(xw + (size_t)s3 * H_F + q * 4);
        acc.x += (v0.x + v1.x) + (v2.x + v3.x);
        acc.y += (v0.y + v1.y) + (v2.y + v3.y);
        acc.z += (v0.z + v1.z) + (v2.z + v3.z);
        acc.w += (v0.w + v1.w) + (v2.w + v3.w);
    }
    for (; i < n; i += 8) {
        unsigned s = cp[i];
        float4 v = *(const float4*)(xw + (size_t)s * H_F + q * 4);
        acc.x += v.x; acc.y += v.y; acc.z += v.z; acc.w += v.w;
    }
#pragma unroll
    for (int st = 8; st < 64; st <<= 1) {
        acc.x += __shfl_xor(acc.x, st, 64);
        acc.y += __shfl_xor(acc.y, st, 64);
        acc.z += __shfl_xor(acc.z, st, 64);
        acc.w += __shfl_xor(acc.w, st, 64);
    }
    if (g == 0) {
        float dv = dinv[d];
        float4 sv = *(const float4*)(xw + (size_t)d * H_F + q * 4);   // self-loop
        float4 sc = *(const float4*)(scale + q * 4);
        float4 sh = *(const float4*)(shift + q * 4);
        float4 h;
        h.x = fmaxf(fmaf((acc.x + sv.x) * dv, sc.x, sh.x), 0.f) * dv;
        h.y = fmaxf(fmaf((acc.y + sv.y) * dv, sc.y, sh.y), 0.f) * dv;
        h.z = fmaxf(fmaf((acc.z + sv.z) * dv, sc.z, sh.z), 0.f) * dv;
        h.w = fmaxf(fmaf((acc.w + sv.w) * dv, sc.w, sh.w), 0.f) * dv;
        *(float4*)(hs + (size_t)d * H_F + q * 4) = h;
    }
}

// ---------------- gather2 + out-GEMM fused, software-pipelined ----------------
__global__ __launch_bounds__(256) void k_gather2(const unsigned* __restrict__ off,
                                                 const unsigned* __restrict__ deg,
                                                 const unsigned* __restrict__ csr,
                                                 const float* __restrict__ hs,
                                                 const float* __restrict__ dinv,
                                                 const float* __restrict__ W2,
                                                 const float* __restrict__ b2,
                                                 float* __restrict__ out) {
    __shared__ float ws[H_F * OUT_F];   // 8 KB
    __shared__ float bs[OUT_F];
    for (int i = threadIdx.x; i < H_F * OUT_F; i += 256) ws[i] = W2[i];
    if (threadIdx.x < OUT_F) bs[threadIdx.x] = b2[threadIdx.x];
    __syncthreads();
    int wid  = threadIdx.x >> 6;
    int lane = threadIdx.x & 63;
    int g    = lane >> 3;
    int q    = lane & 7;
    int d = blockIdx.x * 4 + wid;
    const unsigned* cp = csr + off[d];
    unsigned n = deg[d];
    float4 acc = make_float4(0.f, 0.f, 0.f, 0.f);
    unsigned i = g;
    for (; i + 24 < n; i += 32) {
        unsigned s0 = cp[i], s1 = cp[i + 8], s2 = cp[i + 16], s3 = cp[i + 24];
        float4 v0 = *(const float4*)(hs + (size_t)s0 * H_F + q * 4);
        float4 v1 = *(const float4*)(hs + (size_t)s1 * H_F + q * 4);
        float4 v2 = *(const float4*)(hs + (size_t)s2 * H_F + q * 4);
        float4 v3 = *(const float4*)(hs + (size_t)s3 * H_F + q * 4);
        acc.x += (v0.x + v1.x) + (v2.x + v3.x);
        acc.y += (v0.y + v1.y) + (v2.y + v3.y);
        acc.z += (v0.z + v1.z) + (v2.z + v3.z);
        acc.w += (v0.w + v1.w) + (v2.w + v3.w);
    }
    for (; i < n; i += 8) {
        unsigned s = cp[i];
        float4 v = *(const float4*)(hs + (size_t)s * H_F + q * 4);
        acc.x += v.x; acc.y += v.y; acc.z += v.z; acc.w += v.w;
    }
#pragma unroll
    for (int st = 8; st < 64; st <<= 1) {
        acc.x += __shfl_xor(acc.x, st, 64);
        acc.y += __shfl_xor(acc.y, st, 64);
        acc.z += __shfl_xor(acc.z, st, 64);
        acc.w += __shfl_xor(acc.w, st, 64);
    }
    float dv = dinv[d];
    float4 sv = *(const float4*)(hs + (size_t)d * H_F + q * 4);       // self-loop
    float tv[4];
    tv[0] = (acc.x + sv.x) * dv;
    tv[1] = (acc.y + sv.y) * dv;
    tv[2] = (acc.z + sv.z) * dv;
    tv[3] = (acc.w + sv.w) * dv;
    float o = bs[lane];
#pragma unroll
    for (int k = 0; k < H_F; ++k) {
        float a = __shfl(tv[k & 3], k >> 2, 8);
        o = fmaf(a, ws[k * OUT_F + lane], o);
    }
    out[(size_t)d * OUT_F + lane] = o;
}

extern "C" void kernel_launch(void* const* d_in, const int* in_sizes, int n_in,
                              void* d_out, int out_size, void* d_ws, size_t ws_size,
                              hipStream_t stream) {
    const float* x     = (const float*)d_in[0];
    const int*   ei    = (const int*)d_in[1];
    const float* W1    = (const float*)d_in[2];
    const float* b1    = (const float*)d_in[3];
    const float* W2    = (const float*)d_in[4];
    const float* b2    = (const float*)d_in[5];
    const float* gamma = (const float*)d_in[6];
    const float* beta  = (const float*)d_in[7];
    const float* rm    = (const float*)d_in[8];
    const float* rv    = (const float*)d_in[9];
    float* out = (float*)d_out;

    const int* src = ei;
    const int* dst = ei + E_EDGES;

    // workspace layout (~40 MB). packed aliases hs — lifetimes disjoint
    float*    xw     = (float*)d_ws;                    // N*32
    float*    hs     = xw + (size_t)N_NODES * H_F;      // N*32  (alias: packed)
    unsigned* packed = (unsigned*)hs;                   // E  (E == N*32)
    unsigned* csr    = (unsigned*)(hs + (size_t)N_NODES * H_F);  // E
    float*    dinv   = (float*)(csr + E_EDGES);         // N
    unsigned* off    = (unsigned*)(dinv + N_NODES);     // N
    unsigned* deg    = off + N_NODES;                   // N
    float*    scale  = (float*)(deg + N_NODES);         // 32
    float*    shift  = scale + H_F;                     // 32
    unsigned* binCnt = (unsigned*)(shift + H_F);        // NBINS
    unsigned* binPos = binCnt + NBINS;                  // NBINS
    unsigned* binOff = binPos + NBINS;                  // NBINS

    k_prep<<<(NBINS + 255) / 256, 256, 0, stream>>>(gamma, beta, rm, rv, b1,
                                                    scale, shift, binCnt, binPos);
    k_hist<<<512, 256, 0, stream>>>(dst, binCnt);
    k_scanbins<<<1, 256, 0, stream>>>(binCnt, binOff);
    k_binfill<<<(E_EDGES + CHUNK - 1) / CHUNK, 256, 0, stream>>>(src, dst, binOff, binPos, packed);
    k_sortbin<<<NBINS, 256, 0, stream>>>(binOff, binCnt, packed, off, deg, dinv, csr);

    k_gemm1<<<(N_NODES + TM - 1) / TM, 256, 0, stream>>>(x, W1, dinv, xw);
    k_gather1<<<N_NODES / 4, 256, 0, stream>>>(off, deg, csr, xw, dinv, scale, shift, hs);
    k_gather2<<<N_NODES / 4, 256, 0, stream>>>(off, deg, csr, hs, dinv, W2, b2, out);
}

// Round 7
// 322.826 us; speedup vs baseline: 7.5486x; 1.1284x over previous
//
#include <hip/hip_runtime.h>
#include <hip/hip_fp16.h>

#define N_NODES 100000
#define E_EDGES 3200000
#define IN_F 512
#define H_F 32
#define OUT_F 64
#define BN_EPS 1e-5f
#define NBINS 1563              // ceil(100000 / 64), 64 nodes per bin
#define CHUNK 16384             // edges per binfill block

struct H8 { __half2 h[4]; };    // 16B = 8 halves
struct H4 { __half2 a, b; };    // 8B  = 4 halves

// ---------------- prep: zero bin counters + BN fold ----------------
__global__ __launch_bounds__(256) void k_prep(const float* __restrict__ gamma,
                                              const float* __restrict__ beta,
                                              const float* __restrict__ rm,
                                              const float* __restrict__ rv,
                                              const float* __restrict__ b1,
                                              float* __restrict__ scale,
                                              float* __restrict__ shift,
                                              unsigned* __restrict__ binCnt,
                                              unsigned* __restrict__ binPos) {
    int t = blockIdx.x * 256 + threadIdx.x;
    if (t < NBINS) { binCnt[t] = 0u; binPos[t] = 0u; }
    if (blockIdx.x == 0 && threadIdx.x < H_F) {
        int k = threadIdx.x;
        float s = gamma[k] * rsqrtf(rv[k] + BN_EPS);
        scale[k] = s;
        shift[k] = (b1[k] - rm[k]) * s + beta[k];
    }
}

// ---------------- bin histogram (LDS-privatized) ----------------
__global__ __launch_bounds__(256) void k_hist(const int* __restrict__ dst,
                                              unsigned* __restrict__ binCnt) {
    __shared__ unsigned h[NBINS];
    for (int i = threadIdx.x; i < NBINS; i += 256) h[i] = 0;
    __syncthreads();
    for (int e = blockIdx.x * 256 + threadIdx.x; e < E_EDGES; e += 256 * 512)
        atomicAdd(&h[((unsigned)dst[e]) >> 6], 1u);
    __syncthreads();
    for (int i = threadIdx.x; i < NBINS; i += 256) {
        unsigned v = h[i];
        if (v) atomicAdd(&binCnt[i], v);
    }
}

// ---------------- exclusive scan over 1563 bins (1 block) ----------------
__global__ __launch_bounds__(256) void k_scanbins(const unsigned* __restrict__ binCnt,
                                                  unsigned* __restrict__ binOff) {
    __shared__ unsigned carry;
    __shared__ unsigned wtot[4];
    if (threadIdx.x == 0) carry = 0;
    __syncthreads();
    int lane = threadIdx.x & 63, wid = threadIdx.x >> 6;
    for (int base = 0; base < NBINS; base += 256) {
        int i = base + (int)threadIdx.x;
        unsigned v = (i < NBINS) ? binCnt[i] : 0u;
        unsigned xs = v;
#pragma unroll
        for (int s = 1; s < 64; s <<= 1) {
            unsigned t = __shfl_up(xs, s, 64);
            if (lane >= s) xs += t;
        }
        if (lane == 63) wtot[wid] = xs;
        __syncthreads();
        unsigned wbase = 0, tot = 0;
#pragma unroll
        for (int w = 0; w < 4; ++w) { if (w < wid) wbase += wtot[w]; tot += wtot[w]; }
        if (i < NBINS) binOff[i] = carry + wbase + xs - v;
        __syncthreads();
        if (threadIdx.x == 0) carry += tot;
        __syncthreads();
    }
}

// ---------------- bin fill with per-block range reservation ----------------
__global__ __launch_bounds__(256) void k_binfill(const int* __restrict__ src,
                                                 const int* __restrict__ dst,
                                                 const unsigned* __restrict__ binOff,
                                                 unsigned* __restrict__ binPos,
                                                 unsigned* __restrict__ packed) {
    __shared__ unsigned h[NBINS];
    for (int i = threadIdx.x; i < NBINS; i += 256) h[i] = 0;
    __syncthreads();
    int e0 = blockIdx.x * CHUNK;
    int e1 = min(e0 + CHUNK, E_EDGES);
    for (int e = e0 + threadIdx.x; e < e1; e += 256)
        atomicAdd(&h[((unsigned)dst[e]) >> 6], 1u);
    __syncthreads();
    for (int i = threadIdx.x; i < NBINS; i += 256) {
        unsigned c = h[i];
        h[i] = c ? atomicAdd(&binPos[i], c) : 0u;   // reserved base (bin-relative)
    }
    __syncthreads();
    for (int e = e0 + threadIdx.x; e < e1; e += 256) {
        unsigned s = (unsigned)src[e];
        unsigned d = (unsigned)dst[e];
        unsigned bin = d >> 6;
        unsigned pos = atomicAdd(&h[bin], 1u);      // LDS bump within reserved range
        packed[binOff[bin] + pos] = ((d & 63u) << 17) | s;
    }
}

// ---------------- per-bin sort to per-node CSR + deg/dinv/off ----------------
__global__ __launch_bounds__(256) void k_sortbin(const unsigned* __restrict__ binOff,
                                                 const unsigned* __restrict__ binCnt,
                                                 const unsigned* __restrict__ packed,
                                                 unsigned* __restrict__ off,
                                                 unsigned* __restrict__ deg,
                                                 float* __restrict__ dinv,
                                                 unsigned* __restrict__ csr) {
    __shared__ unsigned cnt[64];
    __shared__ unsigned cur[64];
    int bin = blockIdx.x;
    if (threadIdx.x < 64) cnt[threadIdx.x] = 0;
    __syncthreads();
    unsigned base = binOff[bin], len = binCnt[bin];
    for (unsigned j = threadIdx.x; j < len; j += 256)
        atomicAdd(&cnt[packed[base + j] >> 17], 1u);
    __syncthreads();
    if (threadIdx.x < 64) {   // wave 0: exclusive scan over the 64 local nodes
        unsigned v = cnt[threadIdx.x];
        unsigned xs = v;
#pragma unroll
        for (int s = 1; s < 64; s <<= 1) {
            unsigned t = __shfl_up(xs, s, 64);
            if ((int)threadIdx.x >= s) xs += t;
        }
        unsigned loc = xs - v;
        cur[threadIdx.x] = loc;
        int node = bin * 64 + (int)threadIdx.x;
        if (node < N_NODES) {
            off[node]  = base + loc;
            deg[node]  = v;
            dinv[node] = rsqrtf((float)v + 1.0f);   // +1 self-loop
        }
    }
    __syncthreads();
    for (unsigned j = threadIdx.x; j < len; j += 256) {
        unsigned p = packed[base + j];
        unsigned pos = atomicAdd(&cur[p >> 17], 1u);
        csr[base + pos] = p & 0x1FFFFu;             // global src index
    }
}

// ---------------- GEMM1: xw16 = fp16((x @ W1) * dinv[row]) ----------------
#define TM 128
#define TK 32
__global__ __launch_bounds__(256) void k_gemm1(const float* __restrict__ x,
                                               const float* __restrict__ W1,
                                               const float* __restrict__ dinv,
                                               __half* __restrict__ xw16) {
    __shared__ float xs[TM * TK];   // quad-swizzled
    __shared__ float ws[TK * H_F];
    const int t   = threadIdx.x;
    const int tr  = t >> 3;
    const int tq  = t & 7;
    const int c0  = tq * 4;
    const int swz = tr & 7;
    const int row0 = blockIdx.x * TM;
    float acc[4][4] = {};
    for (int k0 = 0; k0 < IN_F; k0 += TK) {
#pragma unroll
        for (int p = 0; p < 4; ++p) {
            int r = p * 32 + tr;
            int gr = row0 + r;
            if (gr >= N_NODES) gr = N_NODES - 1;
            float4 v = *(const float4*)(x + (size_t)gr * IN_F + k0 + tq * 4);
            *(float4*)&xs[r * TK + ((tq ^ (r & 7)) << 2)] = v;
        }
        {
            float4 v = *(const float4*)(W1 + (size_t)(k0 + tr) * H_F + tq * 4);
            *(float4*)&ws[tr * H_F + tq * 4] = v;
        }
        __syncthreads();
#pragma unroll
        for (int kk = 0; kk < TK; kk += 4) {
            float xr[4][4], wr[4][4];
            const int q = ((kk >> 2) ^ swz) << 2;
#pragma unroll
            for (int i = 0; i < 4; ++i) {
                float4 v = *(const float4*)&xs[(tr + 32 * i) * TK + q];
                xr[i][0] = v.x; xr[i][1] = v.y; xr[i][2] = v.z; xr[i][3] = v.w;
            }
#pragma unroll
            for (int j = 0; j < 4; ++j) {
                float4 v = *(const float4*)&ws[(kk + j) * H_F + c0];
                wr[j][0] = v.x; wr[j][1] = v.y; wr[j][2] = v.z; wr[j][3] = v.w;
            }
#pragma unroll
            for (int k = 0; k < 4; ++k)
#pragma unroll
                for (int i = 0; i < 4; ++i)
#pragma unroll
                    for (int j = 0; j < 4; ++j)
                        acc[i][j] = fmaf(xr[i][k], wr[k][j], acc[i][j]);
        }
        __syncthreads();
    }
#pragma unroll
    for (int i = 0; i < 4; ++i) {
        int r = row0 + tr + 32 * i;
        if (r < N_NODES) {
            float dv = dinv[r];
            H4 o;
            o.a = __floats2half2_rn(acc[i][0] * dv, acc[i][1] * dv);
            o.b = __floats2half2_rn(acc[i][2] * dv, acc[i][3] * dv);
            *(H4*)(xw16 + (size_t)r * H_F + c0) = o;
        }
    }
}

__device__ inline void acc8(float* acc, float4 raw) {
    const __half2* h = (const __half2*)&raw;
#pragma unroll
    for (int j = 0; j < 4; ++j) {
        float2 f = __half22float2(h[j]);
        acc[2 * j]     += f.x;
        acc[2 * j + 1] += f.y;
    }
}

// ---------------- gather1: 2 nodes/wave, 8 groups x 4 lanes x 16B, 4-deep ----------------
__global__ __launch_bounds__(256) void k_gather1(const unsigned* __restrict__ off,
                                                 const unsigned* __restrict__ deg,
                                                 const unsigned* __restrict__ csr,
                                                 const __half* __restrict__ xw16,
                                                 const float* __restrict__ dinv,
                                                 const float* __restrict__ scale,
                                                 const float* __restrict__ shift,
                                                 __half* __restrict__ hs16) {
    int lane  = threadIdx.x & 63;
    int ll    = lane & 31;          // lane within half-wave
    int g     = ll >> 2;            // 0..7 edge group
    int q     = ll & 3;             // channel quarter (8 ch)
    int d = blockIdx.x * 8 + ((threadIdx.x >> 6) << 1) + (lane >> 5);   // N = 8*12500
    const unsigned* cp = csr + off[d];
    unsigned n = deg[d];
    float acc[8] = {};
    unsigned i = g;
    for (; i + 24 < n; i += 32) {
        unsigned s0 = cp[i], s1 = cp[i + 8], s2 = cp[i + 16], s3 = cp[i + 24];
        float4 r0 = *(const float4*)(xw16 + (size_t)s0 * H_F + q * 8);
        float4 r1 = *(const float4*)(xw16 + (size_t)s1 * H_F + q * 8);
        float4 r2 = *(const float4*)(xw16 + (size_t)s2 * H_F + q * 8);
        float4 r3 = *(const float4*)(xw16 + (size_t)s3 * H_F + q * 8);
        acc8(acc, r0); acc8(acc, r1); acc8(acc, r2); acc8(acc, r3);
    }
    for (; i < n; i += 8) {
        float4 r = *(const float4*)(xw16 + (size_t)cp[i] * H_F + q * 8);
        acc8(acc, r);
    }
#pragma unroll
    for (int st = 4; st <= 16; st <<= 1)
#pragma unroll
        for (int j = 0; j < 8; ++j)
            acc[j] += __shfl_xor(acc[j], st, 64);
    if (g == 0) {
        float dv = dinv[d];
        float sf[8];
        {   // self-loop row
            float4 raw = *(const float4*)(xw16 + (size_t)d * H_F + q * 8);
            const __half2* h = (const __half2*)&raw;
#pragma unroll
            for (int j = 0; j < 4; ++j) {
                float2 f = __half22float2(h[j]);
                sf[2 * j] = f.x; sf[2 * j + 1] = f.y;
            }
        }
        float scf[8], shf[8];
        *(float4*)scf       = *(const float4*)(scale + q * 8);
        *(float4*)(scf + 4) = *(const float4*)(scale + q * 8 + 4);
        *(float4*)shf       = *(const float4*)(shift + q * 8);
        *(float4*)(shf + 4) = *(const float4*)(shift + q * 8 + 4);
        H8 o;
#pragma unroll
        for (int j = 0; j < 4; ++j) {
            float a0 = (acc[2 * j]     + sf[2 * j])     * dv;
            float a1 = (acc[2 * j + 1] + sf[2 * j + 1]) * dv;
            float h0 = fmaxf(fmaf(a0, scf[2 * j],     shf[2 * j]),     0.f) * dv;
            float h1 = fmaxf(fmaf(a1, scf[2 * j + 1], shf[2 * j + 1]), 0.f) * dv;
            o.h[j] = __floats2half2_rn(h0, h1);
        }
        *(H8*)(hs16 + (size_t)d * H_F + q * 8) = o;
    }
}

// ---------------- gather2 + out-GEMM fused ----------------
__global__ __launch_bounds__(256) void k_gather2(const unsigned* __restrict__ off,
                                                 const unsigned* __restrict__ deg,
                                                 const unsigned* __restrict__ csr,
                                                 const __half* __restrict__ hs16,
                                                 const float* __restrict__ dinv,
                                                 const float* __restrict__ W2,
                                                 const float* __restrict__ b2,
                                                 float* __restrict__ out) {
    __shared__ float ws[H_F * OUT_F];   // 8 KB
    __shared__ float bs[OUT_F];
    for (int i = threadIdx.x; i < H_F * OUT_F; i += 256) ws[i] = W2[i];
    if (threadIdx.x < OUT_F) bs[threadIdx.x] = b2[threadIdx.x];
    __syncthreads();
    int lane  = threadIdx.x & 63;
    int ll    = lane & 31;
    int g     = ll >> 2;
    int q     = ll & 3;
    int d = blockIdx.x * 8 + ((threadIdx.x >> 6) << 1) + (lane >> 5);
    const unsigned* cp = csr + off[d];
    unsigned n = deg[d];
    float acc[8] = {};
    unsigned i = g;
    for (; i + 24 < n; i += 32) {
        unsigned s0 = cp[i], s1 = cp[i + 8], s2 = cp[i + 16], s3 = cp[i + 24];
        float4 r0 = *(const float4*)(hs16 + (size_t)s0 * H_F + q * 8);
        float4 r1 = *(const float4*)(hs16 + (size_t)s1 * H_F + q * 8);
        float4 r2 = *(const float4*)(hs16 + (size_t)s2 * H_F + q * 8);
        float4 r3 = *(const float4*)(hs16 + (size_t)s3 * H_F + q * 8);
        acc8(acc, r0); acc8(acc, r1); acc8(acc, r2); acc8(acc, r3);
    }
    for (; i < n; i += 8) {
        float4 r = *(const float4*)(hs16 + (size_t)cp[i] * H_F + q * 8);
        acc8(acc, r);
    }
#pragma unroll
    for (int st = 4; st <= 16; st <<= 1)
#pragma unroll
        for (int j = 0; j < 8; ++j)
            acc[j] += __shfl_xor(acc[j], st, 64);
    float tv[8];
#pragma unroll
    for (int j = 0; j < 8; ++j) tv[j] = 0.f;
    if (g == 0) {
        float dv = dinv[d];
        float4 raw = *(const float4*)(hs16 + (size_t)d * H_F + q * 8);
        const __half2* h = (const __half2*)&raw;
#pragma unroll
        for (int j = 0; j < 4; ++j) {
            float2 f = __half22float2(h[j]);
            tv[2 * j]     = (acc[2 * j]     + f.x) * dv;
            tv[2 * j + 1] = (acc[2 * j + 1] + f.y) * dv;
        }
    }
    float o0 = bs[ll], o1 = bs[ll + 32];
#pragma unroll
    for (int k = 0; k < H_F; ++k) {
        float a = __shfl(tv[k & 7], k >> 3, 32);   // owner lane q = k>>3 in this half
        o0 = fmaf(a, ws[k * OUT_F + ll],      o0);
        o1 = fmaf(a, ws[k * OUT_F + ll + 32], o1);
    }
    out[(size_t)d * OUT_F + ll]      = o0;
    out[(size_t)d * OUT_F + ll + 32] = o1;
}

extern "C" void kernel_launch(void* const* d_in, const int* in_sizes, int n_in,
                              void* d_out, int out_size, void* d_ws, size_t ws_size,
                              hipStream_t stream) {
    const float* x     = (const float*)d_in[0];
    const int*   ei    = (const int*)d_in[1];
    const float* W1    = (const float*)d_in[2];
    const float* b1    = (const float*)d_in[3];
    const float* W2    = (const float*)d_in[4];
    const float* b2    = (const float*)d_in[5];
    const float* gamma = (const float*)d_in[6];
    const float* beta  = (const float*)d_in[7];
    const float* rm    = (const float*)d_in[8];
    const float* rv    = (const float*)d_in[9];
    float* out = (float*)d_out;

    const int* src = ei;
    const int* dst = ei + E_EDGES;

    // workspace layout. packed (E u32 = 12.8MB) aliases xw16+hs16 (N*32 half
    // each = 12.8MB combined) — lifetimes disjoint (packed: binfill..sortbin;
    // xw16 written by gemm1 after sortbin).
    __half*   xw16   = (__half*)d_ws;                   // N*32 half
    __half*   hs16   = xw16 + (size_t)N_NODES * H_F;    // N*32 half
    unsigned* packed = (unsigned*)d_ws;                 // E u32 (alias)
    unsigned* csr    = (unsigned*)(hs16 + (size_t)N_NODES * H_F);  // E u32
    float*    dinv   = (float*)(csr + E_EDGES);         // N
    unsigned* off    = (unsigned*)(dinv + N_NODES);     // N
    unsigned* deg    = off + N_NODES;                   // N
    float*    scale  = (float*)(deg + N_NODES);         // 32
    float*    shift  = scale + H_F;                     // 32
    unsigned* binCnt = (unsigned*)(shift + H_F);        // NBINS
    unsigned* binPos = binCnt + NBINS;                  // NBINS
    unsigned* binOff = binPos + NBINS;                  // NBINS

    k_prep<<<(NBINS + 255) / 256, 256, 0, stream>>>(gamma, beta, rm, rv, b1,
                                                    scale, shift, binCnt, binPos);
    k_hist<<<512, 256, 0, stream>>>(dst, binCnt);
    k_scanbins<<<1, 256, 0, stream>>>(binCnt, binOff);
    k_binfill<<<(E_EDGES + CHUNK - 1) / CHUNK, 256, 0, stream>>>(src, dst, binOff, binPos, packed);
    k_sortbin<<<NBINS, 256, 0, stream>>>(binOff, binCnt, packed, off, deg, dinv, csr);

    k_gemm1<<<(N_NODES + TM - 1) / TM, 256, 0, stream>>>(x, W1, dinv, xw16);
    k_gather1<<<N_NODES / 8, 256, 0, stream>>>(off, deg, csr, xw16, dinv, scale, shift, hs16);
    k_gather2<<<N_NODES / 8, 256, 0, stream>>>(off, deg, csr, hs16, dinv, W2, b2, out);
}